// Round 1
// baseline (219.008 us; speedup 1.0000x reference)
//
#include <hip/hip_runtime.h>
#include <math.h>

#define BLOCK 256

// ---------------------------------------------------------------------------
// Kernel 1: zero the packed per-box (iou, ~anchor) atomic accumulators.
// ws is re-poisoned 0xAA before every timed launch, so this must run each call.
// ---------------------------------------------------------------------------
__global__ void __launch_bounds__(BLOCK) bbp_init(unsigned long long* __restrict__ packed, int n) {
    int i = blockIdx.x * BLOCK + threadIdx.x;
    if (i < n) packed[i] = 0ull;
}

// ---------------------------------------------------------------------------
// Kernel 2: per-anchor IoU row. Computes:
//   max_iou_anchor[b,a], box_indice[b,a] (first argmax over boxes),
//   packed[b,n] = max over anchors of (iou_bits<<32 | (0xFFFFFFFF - a))
//     -> upper 32 bits = max_iou_of_bbox, lower = first argmax anchor index
//   winner[b,a] = -1 (init for the scatter kernel)
// ---------------------------------------------------------------------------
__global__ void __launch_bounds__(BLOCK) bbp_match(
    const float* __restrict__ anchors,            // [A,4] cbox (cx,cy,w,h)
    const float* __restrict__ bboxes,             // [B,N,4] bbox (x1,y1,x2,y2)
    float* __restrict__ max_iou_anchor,           // [B,A]
    int* __restrict__ box_indice,                 // [B,A]
    int* __restrict__ winner,                     // [B,A], init to -1 here
    unsigned long long* __restrict__ packed,      // [B,N]
    int A, int N) {
    const int b = blockIdx.y;
    const int tid = threadIdx.x;
    const int a = blockIdx.x * BLOCK + tid;
    const int lane = tid & 63;
    const int wid = tid >> 6;
    const int NW = BLOCK / 64;

    extern __shared__ char smem_raw[];
    float* sb = (float*)smem_raw;              // [N*4] boxes
    float* sarea = sb + 4 * N;                 // [N] box areas
    unsigned long long* spart =
        (unsigned long long*)(smem_raw + ((5 * N * 4 + 7) & ~7)); // [N*NW]

    for (int i = tid; i < N * 4; i += BLOCK) sb[i] = bboxes[(size_t)b * N * 4 + i];
    __syncthreads();
    for (int i = tid; i < N; i += BLOCK)
        sarea[i] = (sb[4 * i + 2] - sb[4 * i]) * (sb[4 * i + 3] - sb[4 * i + 1]);
    __syncthreads();

    const int aa = (a < A) ? a : (A - 1);
    const float4 ac = *(const float4*)(anchors + (size_t)aa * 4);
    const float ax1 = ac.x - ac.z * 0.5f;
    const float ay1 = ac.y - ac.w * 0.5f;
    const float ax2 = ac.x + ac.z * 0.5f;
    const float ay2 = ac.y + ac.w * 0.5f;
    const float area_a = (ax2 - ax1) * (ay2 - ay1);

    float best = -1.0f;
    int bi = 0;
    for (int n = 0; n < N; ++n) {
        float bx1 = sb[4 * n], by1 = sb[4 * n + 1], bx2 = sb[4 * n + 2], by2 = sb[4 * n + 3];
        float lx = fmaxf(ax1, bx1), ly = fmaxf(ay1, by1);
        float rx = fminf(ax2, bx2), ry = fminf(ay2, by2);
        float w = fmaxf(rx - lx, 0.0f), h = fmaxf(ry - ly, 0.0f);
        float inter = w * h;
        float iou = inter / (area_a + sarea[n] - inter);
        if (iou > best) { best = iou; bi = n; }   // strict > keeps FIRST argmax (JAX semantics)

        // packed key: higher iou wins; tie -> smaller anchor index wins (first occurrence)
        unsigned long long pk = ((unsigned long long)__float_as_uint(iou) << 32)
                              | (unsigned long long)(0xFFFFFFFFu - (unsigned)a);
        if (a >= A) pk = 0ull;
        #pragma unroll
        for (int off = 32; off > 0; off >>= 1) {
            unsigned long long o = __shfl_down(pk, off, 64);
            if (o > pk) pk = o;
        }
        if (lane == 0) spart[n * NW + wid] = pk;
    }
    __syncthreads();
    for (int n = tid; n < N; n += BLOCK) {
        unsigned long long pk = spart[n * NW];
        #pragma unroll
        for (int j = 1; j < NW; ++j) {
            unsigned long long o = spart[n * NW + j];
            if (o > pk) pk = o;
        }
        atomicMax(&packed[(size_t)b * N + n], pk);
    }
    if (a < A) {
        size_t idx = (size_t)b * A + a;
        max_iou_anchor[idx] = best;
        box_indice[idx] = bi;
        winner[idx] = -1;
    }
}

// ---------------------------------------------------------------------------
// Kernel 3: segment_max(tgt_ids, anchor_indice) -> winner[b,a] via atomicMax.
// ---------------------------------------------------------------------------
__global__ void __launch_bounds__(BLOCK) bbp_scatter(
    const unsigned long long* __restrict__ packed, int* __restrict__ winner,
    int A, int N, int B) {
    int i = blockIdx.x * BLOCK + threadIdx.x;
    if (i >= B * N) return;
    int b = i / N;
    int n = i - b * N;
    unsigned an = 0xFFFFFFFFu - (unsigned)(packed[i] & 0xFFFFFFFFull);
    if (an < (unsigned)A)
        atomicMax(&winner[(size_t)b * A + an], n);
}

// ---------------------------------------------------------------------------
// Kernel 4: apply override, score, one-hot conf, and delta encoding.
// ---------------------------------------------------------------------------
__global__ void __launch_bounds__(BLOCK) bbp_finalize(
    const float* __restrict__ anchors, const float* __restrict__ bboxes,
    const int* __restrict__ labels, const float* __restrict__ mean4,
    const float* __restrict__ std4, const float* __restrict__ thr_p,
    const float* __restrict__ max_iou_anchor, const int* __restrict__ box_indice,
    const int* __restrict__ winner, const unsigned long long* __restrict__ packed,
    float* __restrict__ out_conf, float* __restrict__ out_deltas,
    int A, int N, int C) {
    const int b = blockIdx.y;
    const int a = blockIdx.x * BLOCK + threadIdx.x;
    if (a >= A) return;
    const float thr = thr_p[0];
    const size_t idx = (size_t)b * A + a;

    int w = winner[idx];
    bool valid = (w >= 0);
    int bi = valid ? w : box_indice[idx];
    float miou = valid ? __uint_as_float((unsigned)(packed[(size_t)b * N + w] >> 32))
                       : max_iou_anchor[idx];
    float mb = __uint_as_float((unsigned)(packed[(size_t)b * N + bi] >> 32));
    float denom = fmaxf(mb, thr);
    if (miou < thr * 0.5f) miou = 0.0f;
    float score = miou / denom;
    int lab = labels[(size_t)b * N + bi];
    if (lab <= 0) { score = 0.0f; lab = 0; }

    for (int c = 0; c < C; ++c)
        out_conf[idx * C + c] = (lab == c + 1) ? score : 0.0f;

    float4 bb = *(const float4*)(bboxes + ((size_t)b * N + bi) * 4);
    float4 ac = *(const float4*)(anchors + (size_t)a * 4);
    float cx = (bb.x + bb.z) * 0.5f;
    float cy = (bb.y + bb.w) * 0.5f;
    float bw = bb.z - bb.x;
    float bh = bb.w - bb.y;
    float4 d;
    d.x = ((cx - ac.x) / ac.z - mean4[0]) / std4[0];
    d.y = ((cy - ac.y) / ac.w - mean4[1]) / std4[1];
    d.z = (logf(bw / ac.z) - mean4[2]) / std4[2];
    d.w = (logf(bh / ac.w) - mean4[3]) / std4[3];
    *(float4*)(out_deltas + idx * 4) = d;
}

// ---------------------------------------------------------------------------
extern "C" void kernel_launch(void* const* d_in, const int* in_sizes, int n_in,
                              void* d_out, int out_size, void* d_ws, size_t ws_size,
                              hipStream_t stream) {
    const float* anchors = (const float*)d_in[0];
    const int* labels = (const int*)d_in[1];
    const float* bboxes = (const float*)d_in[2];
    const float* mean4 = (const float*)d_in[3];
    const float* std4 = (const float*)d_in[4];
    const float* thr_p = (const float*)d_in[5];
    // d_in[6] = num_classes (device scalar) — derived from out_size instead.

    const int A = in_sizes[0] / 4;       // 65536
    const int BN = in_sizes[1];          // 800
    const int N = 100;                   // gt boxes per image (fixed by problem)
    const int B = BN / N;                // 8
    const int C = out_size / (B * A) - 4; // 1  (out = B*A*C conf + B*A*4 deltas)

    // Workspace layout (poisoned 0xAA each launch; everything init'ed below)
    char* ws = (char*)d_ws;
    unsigned long long* packed = (unsigned long long*)ws;                      // [B*N]
    size_t off = ((size_t)B * N * sizeof(unsigned long long) + 255) & ~(size_t)255;
    float* max_iou_anchor = (float*)(ws + off); off += (size_t)B * A * sizeof(float);
    off = (off + 255) & ~(size_t)255;
    int* box_indice = (int*)(ws + off); off += (size_t)B * A * sizeof(int);
    off = (off + 255) & ~(size_t)255;
    int* winner = (int*)(ws + off);

    float* out_conf = (float*)d_out;
    float* out_deltas = out_conf + (size_t)B * A * C;

    bbp_init<<<dim3((B * N + BLOCK - 1) / BLOCK), dim3(BLOCK), 0, stream>>>(packed, B * N);

    dim3 grid((A + BLOCK - 1) / BLOCK, B);
    size_t smem = (size_t)((5 * N * 4 + 7) & ~7)
                + (size_t)N * (BLOCK / 64) * sizeof(unsigned long long);
    bbp_match<<<grid, dim3(BLOCK), smem, stream>>>(anchors, bboxes, max_iou_anchor,
                                                   box_indice, winner, packed, A, N);

    bbp_scatter<<<dim3((B * N + BLOCK - 1) / BLOCK), dim3(BLOCK), 0, stream>>>(
        packed, winner, A, N, B);

    bbp_finalize<<<grid, dim3(BLOCK), 0, stream>>>(anchors, bboxes, labels, mean4, std4,
                                                   thr_p, max_iou_anchor, box_indice,
                                                   winner, packed, out_conf, out_deltas,
                                                   A, N, C);
}

// Round 2
// 132.834 us; speedup vs baseline: 1.6487x; 1.6487x over previous
//
#include <hip/hip_runtime.h>
#include <math.h>

#define BLOCK 256
#define AN 65536
#define NN 100
#define NC 50      // boxes per chunk (2 chunks)

// ---------------------------------------------------------------------------
// Kernel 1: zero the packed per-box (iou, ~anchor) atomic accumulators.
// ---------------------------------------------------------------------------
__global__ void __launch_bounds__(BLOCK) bbp_init(unsigned long long* __restrict__ packed, int n) {
    int i = blockIdx.x * BLOCK + threadIdx.x;
    if (i < n) packed[i] = 0ull;
}

// ---------------------------------------------------------------------------
// Kernel 2: per-anchor IoU rows + transposed per-box block reduction.
//   Phase 1: thread = anchor; 100 IoUs; per-anchor argmax in registers;
//            each IoU stored to LDS tile [NC][257] (padded, conflict-free).
//   Phase 2: 200 threads scan 64-element column quarters (box-major),
//            combine quarters via packed u64 max, 1 atomicMax/(block,box).
// ---------------------------------------------------------------------------
__global__ void __launch_bounds__(BLOCK) bbp_match(
    const float* __restrict__ anchors,            // [A,4] cbox (cx,cy,w,h)
    const float* __restrict__ bboxes,             // [B,N,4] bbox
    float* __restrict__ max_iou_anchor,           // [B,A]
    int* __restrict__ box_indice,                 // [B,A]
    int* __restrict__ winner,                     // [B,A] -> -1
    unsigned long long* __restrict__ packed,      // [B,N]
    int A, int N) {
    const int b = blockIdx.y;
    const int tid = threadIdx.x;
    const int a = blockIdx.x * BLOCK + tid;

    __shared__ float sb[4 * NN + NN];          // boxes + areas
    __shared__ float tile[NC * 257];           // iou tile, padded stride 257
    unsigned long long* spart = (unsigned long long*)tile;  // aliased (barriered)

    for (int i = tid; i < 4 * NN; i += BLOCK) sb[i] = bboxes[(size_t)b * 4 * NN + i];
    __syncthreads();
    for (int i = tid; i < NN; i += BLOCK)
        sb[4 * NN + i] = (sb[4 * i + 2] - sb[4 * i]) * (sb[4 * i + 3] - sb[4 * i + 1]);
    __syncthreads();

    const int aa = (a < A) ? a : (A - 1);
    const float4 ac = *(const float4*)(anchors + (size_t)aa * 4);
    const float ax1 = ac.x - ac.z * 0.5f;
    const float ay1 = ac.y - ac.w * 0.5f;
    const float ax2 = ac.x + ac.z * 0.5f;
    const float ay2 = ac.y + ac.w * 0.5f;
    const float area_a = (ax2 - ax1) * (ay2 - ay1);

    float best = -1.0f;
    int bi = 0;
    #pragma unroll
    for (int c = 0; c < 2; ++c) {
        const int n0 = c * NC;
        // ---- phase 1: compute IoUs for this chunk, fill tile ----
        for (int k = 0; k < NC; ++k) {
            const int n = n0 + k;
            const float4 bb = *(const float4*)(sb + 4 * n);
            const float sa = sb[4 * NN + n];
            float lx = fmaxf(ax1, bb.x), ly = fmaxf(ay1, bb.y);
            float rx = fminf(ax2, bb.z), ry = fminf(ay2, bb.w);
            float w = fmaxf(rx - lx, 0.0f), h = fmaxf(ry - ly, 0.0f);
            float inter = w * h;
            float iou = inter / (area_a + sa - inter);
            if (iou > best) { best = iou; bi = n; }   // strict > : first argmax
            tile[k * 257 + tid] = iou;
        }
        __syncthreads();
        // ---- phase 2: box-major column reduce (4 quarters of 64) ----
        unsigned long long pk = 0ull;
        if (tid < 4 * NC) {
            const int n = tid >> 2;
            const int base = (tid & 3) * 64;
            float bm = -1.0f; int bj = base;
            for (int j = 0; j < 64; ++j) {
                float v = tile[n * 257 + base + j];
                if (v > bm) { bm = v; bj = base + j; }   // smallest j on tie
            }
            unsigned anch = (unsigned)(blockIdx.x * BLOCK + bj);
            pk = ((unsigned long long)__float_as_uint(bm) << 32)
               | (unsigned long long)(0xFFFFFFFFu - anch);
        }
        __syncthreads();                       // all tile reads complete
        if (tid < 4 * NC) spart[tid] = pk;     // reuse tile memory
        __syncthreads();
        if (tid < NC) {
            unsigned long long m = spart[4 * tid];
            #pragma unroll
            for (int j = 1; j < 4; ++j) {
                unsigned long long o = spart[4 * tid + j];
                if (o > m) m = o;
            }
            atomicMax(&packed[(size_t)b * N + n0 + tid], m);
        }
        __syncthreads();                       // protect tile before next chunk
    }

    if (a < A) {
        const size_t idx = (size_t)b * A + a;
        max_iou_anchor[idx] = best;
        box_indice[idx] = bi;
        winner[idx] = -1;
    }
}

// ---------------------------------------------------------------------------
// Kernel 3: segment_max(tgt_ids, anchor_indice) -> winner via atomicMax.
// ---------------------------------------------------------------------------
__global__ void __launch_bounds__(BLOCK) bbp_scatter(
    const unsigned long long* __restrict__ packed, int* __restrict__ winner,
    int A, int N, int B) {
    int i = blockIdx.x * BLOCK + threadIdx.x;
    if (i >= B * N) return;
    int b = i / N;
    int n = i - b * N;
    unsigned an = 0xFFFFFFFFu - (unsigned)(packed[i] & 0xFFFFFFFFull);
    if (an < (unsigned)A)
        atomicMax(&winner[(size_t)b * A + an], n);
}

// ---------------------------------------------------------------------------
// Kernel 4: apply override, score, one-hot conf, delta encoding.
// ---------------------------------------------------------------------------
__global__ void __launch_bounds__(BLOCK) bbp_finalize(
    const float* __restrict__ anchors, const float* __restrict__ bboxes,
    const int* __restrict__ labels, const float* __restrict__ mean4,
    const float* __restrict__ std4, const float* __restrict__ thr_p,
    const float* __restrict__ max_iou_anchor, const int* __restrict__ box_indice,
    const int* __restrict__ winner, const unsigned long long* __restrict__ packed,
    float* __restrict__ out_conf, float* __restrict__ out_deltas,
    int A, int N, int C) {
    const int b = blockIdx.y;
    const int a = blockIdx.x * BLOCK + threadIdx.x;
    if (a >= A) return;
    const float thr = thr_p[0];
    const size_t idx = (size_t)b * A + a;

    int w = winner[idx];
    bool valid = (w >= 0);
    int bi = valid ? w : box_indice[idx];
    float miou = valid ? __uint_as_float((unsigned)(packed[(size_t)b * N + w] >> 32))
                       : max_iou_anchor[idx];
    float mb = __uint_as_float((unsigned)(packed[(size_t)b * N + bi] >> 32));
    float denom = fmaxf(mb, thr);
    if (miou < thr * 0.5f) miou = 0.0f;
    float score = miou / denom;
    int lab = labels[(size_t)b * N + bi];
    if (lab <= 0) { score = 0.0f; lab = 0; }

    for (int c = 0; c < C; ++c)
        out_conf[idx * C + c] = (lab == c + 1) ? score : 0.0f;

    float4 bb = *(const float4*)(bboxes + ((size_t)b * N + bi) * 4);
    float4 ac = *(const float4*)(anchors + (size_t)a * 4);
    float cx = (bb.x + bb.z) * 0.5f;
    float cy = (bb.y + bb.w) * 0.5f;
    float bw = bb.z - bb.x;
    float bh = bb.w - bb.y;
    float4 d;
    d.x = ((cx - ac.x) / ac.z - mean4[0]) / std4[0];
    d.y = ((cy - ac.y) / ac.w - mean4[1]) / std4[1];
    d.z = (logf(bw / ac.z) - mean4[2]) / std4[2];
    d.w = (logf(bh / ac.w) - mean4[3]) / std4[3];
    *(float4*)(out_deltas + idx * 4) = d;
}

// ---------------------------------------------------------------------------
extern "C" void kernel_launch(void* const* d_in, const int* in_sizes, int n_in,
                              void* d_out, int out_size, void* d_ws, size_t ws_size,
                              hipStream_t stream) {
    const float* anchors = (const float*)d_in[0];
    const int* labels = (const int*)d_in[1];
    const float* bboxes = (const float*)d_in[2];
    const float* mean4 = (const float*)d_in[3];
    const float* std4 = (const float*)d_in[4];
    const float* thr_p = (const float*)d_in[5];

    const int A = in_sizes[0] / 4;        // 65536
    const int BN = in_sizes[1];           // 800
    const int N = NN;                     // 100
    const int B = BN / N;                 // 8
    const int C = out_size / (B * A) - 4; // 1

    char* ws = (char*)d_ws;
    unsigned long long* packed = (unsigned long long*)ws;                      // [B*N]
    size_t off = ((size_t)B * N * sizeof(unsigned long long) + 255) & ~(size_t)255;
    float* max_iou_anchor = (float*)(ws + off); off += (size_t)B * A * sizeof(float);
    off = (off + 255) & ~(size_t)255;
    int* box_indice = (int*)(ws + off); off += (size_t)B * A * sizeof(int);
    off = (off + 255) & ~(size_t)255;
    int* winner = (int*)(ws + off);

    float* out_conf = (float*)d_out;
    float* out_deltas = out_conf + (size_t)B * A * C;

    bbp_init<<<dim3((B * N + BLOCK - 1) / BLOCK), dim3(BLOCK), 0, stream>>>(packed, B * N);

    dim3 grid((A + BLOCK - 1) / BLOCK, B);
    bbp_match<<<grid, dim3(BLOCK), 0, stream>>>(anchors, bboxes, max_iou_anchor,
                                                box_indice, winner, packed, A, N);

    bbp_scatter<<<dim3((B * N + BLOCK - 1) / BLOCK), dim3(BLOCK), 0, stream>>>(
        packed, winner, A, N, B);

    bbp_finalize<<<grid, dim3(BLOCK), 0, stream>>>(anchors, bboxes, labels, mean4, std4,
                                                   thr_p, max_iou_anchor, box_indice,
                                                   winner, packed, out_conf, out_deltas,
                                                   A, N, C);
}

// Round 3
// 128.623 us; speedup vs baseline: 1.7027x; 1.0327x over previous
//
#include <hip/hip_runtime.h>
#include <math.h>

#define BLOCK 256
#define NN 100

__device__ __forceinline__ float fast_rcp(float x) { return __builtin_amdgcn_rcpf(x); }

// ---------------------------------------------------------------------------
// Kernel 1: zero the packed per-box (iou, ~anchor) atomic accumulators.
// ---------------------------------------------------------------------------
__global__ void __launch_bounds__(BLOCK) bbp_init(unsigned long long* __restrict__ packed, int n) {
    int i = blockIdx.x * BLOCK + threadIdx.x;
    if (i < n) packed[i] = 0ull;
}

// ---------------------------------------------------------------------------
// Kernel 2: per-anchor IoU rows + transposed per-box block reduction.
// Chunked: 32 boxes/chunk (tile 32x257 = 32.9 KB -> 4 blocks/CU).
// Phase 2: 256 threads = 32 boxes x 8 segments x 32 elems, rotated scan
// (<=2-way bank aliasing = free), exact first-argmax tie-break, packed u64
// combine, 1 atomicMax per (block, box).
// ---------------------------------------------------------------------------
template <int CN>
__device__ __forceinline__ void chunk_body(
    int n0, int tid, int blockbase, int b, int N,
    const float* __restrict__ sb, float* __restrict__ tile,
    unsigned long long* __restrict__ spart,
    float ax1, float ay1, float ax2, float ay2, float area_a,
    float& best, int& bi,
    unsigned long long* __restrict__ packed) {
    // ---- phase 1: IoUs for this chunk ----
    #pragma unroll
    for (int k = 0; k < CN; ++k) {
        const int n = n0 + k;
        const float4 bb = *(const float4*)(sb + 4 * n);
        const float sa = sb[4 * NN + n];
        float lx = fmaxf(ax1, bb.x), ly = fmaxf(ay1, bb.y);
        float rx = fminf(ax2, bb.z), ry = fminf(ay2, bb.w);
        float w = fmaxf(rx - lx, 0.0f), h = fmaxf(ry - ly, 0.0f);
        float inter = w * h;
        float iou = inter * fast_rcp(area_a + sa - inter);
        if (iou > best) { best = iou; bi = n; }   // strict > : first argmax
        tile[k * 257 + tid] = iou;
    }
    __syncthreads();
    // ---- phase 2: rotated column scan, (box n, segment s) per thread ----
    if (tid < CN * 8) {
        const int n = tid >> 3;
        const int s = tid & 7;
        float bm = -1.0f; int bgi = 0x7FFFFFFF;
        #pragma unroll
        for (int j = 0; j < 32; ++j) {
            const int e = (j + 4 * s) & 31;
            const int gi = s * 32 + e;
            float v = tile[n * 257 + gi];
            if (v > bm || (v == bm && gi < bgi)) { bm = v; bgi = gi; }
        }
        unsigned anch = (unsigned)(blockbase + bgi);
        spart[n * 9 + s] = ((unsigned long long)__float_as_uint(bm) << 32)
                         | (unsigned long long)(0xFFFFFFFFu - anch);
    }
    __syncthreads();
    if (tid < CN) {
        unsigned long long m = spart[tid * 9];
        #pragma unroll
        for (int j = 1; j < 8; ++j) {
            unsigned long long o = spart[tid * 9 + j];
            if (o > m) m = o;
        }
        atomicMax(&packed[(size_t)b * N + n0 + tid], m);
    }
    // NOTE: no trailing barrier needed: next chunk's phase-1 writes tile,
    // whose reads completed before the barrier above; spart reuse is guarded
    // by the next chunk's post-phase-1 barrier.
}

__global__ void __launch_bounds__(BLOCK) bbp_match(
    const float* __restrict__ anchors,            // [A,4] cbox (cx,cy,w,h)
    const float* __restrict__ bboxes,             // [B,N,4] bbox
    float* __restrict__ max_iou_anchor,           // [B,A]
    int* __restrict__ box_indice,                 // [B,A]
    int* __restrict__ winner,                     // [B,A] -> -1
    unsigned long long* __restrict__ packed,      // [B,N]
    int A, int N) {
    const int b = blockIdx.y;
    const int tid = threadIdx.x;
    const int a = blockIdx.x * BLOCK + tid;
    const int blockbase = blockIdx.x * BLOCK;

    __shared__ float sb[4 * NN + NN];                  // boxes + areas (2 KB)
    __shared__ float tile[32 * 257];                   // iou tile (32.9 KB)
    __shared__ unsigned long long spart[32 * 9];       // partials (2.3 KB)

    for (int i = tid; i < 4 * NN; i += BLOCK) sb[i] = bboxes[(size_t)b * 4 * NN + i];
    __syncthreads();
    for (int i = tid; i < NN; i += BLOCK)
        sb[4 * NN + i] = (sb[4 * i + 2] - sb[4 * i]) * (sb[4 * i + 3] - sb[4 * i + 1]);
    __syncthreads();

    const int aa = (a < A) ? a : (A - 1);
    const float4 ac = *(const float4*)(anchors + (size_t)aa * 4);
    const float ax1 = ac.x - ac.z * 0.5f;
    const float ay1 = ac.y - ac.w * 0.5f;
    const float ax2 = ac.x + ac.z * 0.5f;
    const float ay2 = ac.y + ac.w * 0.5f;
    const float area_a = (ax2 - ax1) * (ay2 - ay1);

    float best = -1.0f;
    int bi = 0;
    chunk_body<32>(0,  tid, blockbase, b, N, sb, tile, spart,
                   ax1, ay1, ax2, ay2, area_a, best, bi, packed);
    chunk_body<32>(32, tid, blockbase, b, N, sb, tile, spart,
                   ax1, ay1, ax2, ay2, area_a, best, bi, packed);
    chunk_body<32>(64, tid, blockbase, b, N, sb, tile, spart,
                   ax1, ay1, ax2, ay2, area_a, best, bi, packed);
    chunk_body<4>(96,  tid, blockbase, b, N, sb, tile, spart,
                   ax1, ay1, ax2, ay2, area_a, best, bi, packed);

    if (a < A) {
        const size_t idx = (size_t)b * A + a;
        max_iou_anchor[idx] = best;
        box_indice[idx] = bi;
        winner[idx] = -1;
    }
}

// ---------------------------------------------------------------------------
// Kernel 3: segment_max(tgt_ids, anchor_indice) -> winner via atomicMax.
// ---------------------------------------------------------------------------
__global__ void __launch_bounds__(BLOCK) bbp_scatter(
    const unsigned long long* __restrict__ packed, int* __restrict__ winner,
    int A, int N, int B) {
    int i = blockIdx.x * BLOCK + threadIdx.x;
    if (i >= B * N) return;
    int b = i / N;
    int n = i - b * N;
    unsigned an = 0xFFFFFFFFu - (unsigned)(packed[i] & 0xFFFFFFFFull);
    if (an < (unsigned)A)
        atomicMax(&winner[(size_t)b * A + an], n);
}

// ---------------------------------------------------------------------------
// Kernel 4: apply override, score, one-hot conf, delta encoding.
// ---------------------------------------------------------------------------
__global__ void __launch_bounds__(BLOCK) bbp_finalize(
    const float* __restrict__ anchors, const float* __restrict__ bboxes,
    const int* __restrict__ labels, const float* __restrict__ mean4,
    const float* __restrict__ std4, const float* __restrict__ thr_p,
    const float* __restrict__ max_iou_anchor, const int* __restrict__ box_indice,
    const int* __restrict__ winner, const unsigned long long* __restrict__ packed,
    float* __restrict__ out_conf, float* __restrict__ out_deltas,
    int A, int N, int C) {
    const int b = blockIdx.y;
    const int a = blockIdx.x * BLOCK + threadIdx.x;
    if (a >= A) return;
    const float thr = thr_p[0];
    const size_t idx = (size_t)b * A + a;

    int w = winner[idx];
    bool valid = (w >= 0);
    int bi = valid ? w : box_indice[idx];
    float miou = valid ? __uint_as_float((unsigned)(packed[(size_t)b * N + w] >> 32))
                       : max_iou_anchor[idx];
    float mb = __uint_as_float((unsigned)(packed[(size_t)b * N + bi] >> 32));
    float denom = fmaxf(mb, thr);
    if (miou < thr * 0.5f) miou = 0.0f;
    float score = miou * fast_rcp(denom);
    int lab = labels[(size_t)b * N + bi];
    if (lab <= 0) { score = 0.0f; lab = 0; }

    for (int c = 0; c < C; ++c)
        out_conf[idx * C + c] = (lab == c + 1) ? score : 0.0f;

    float4 bb = *(const float4*)(bboxes + ((size_t)b * N + bi) * 4);
    float4 ac = *(const float4*)(anchors + (size_t)a * 4);
    float cx = (bb.x + bb.z) * 0.5f;
    float cy = (bb.y + bb.w) * 0.5f;
    float bw = bb.z - bb.x;
    float bh = bb.w - bb.y;
    const float rz = fast_rcp(ac.z), rw = fast_rcp(ac.w);
    float4 d;
    d.x = ((cx - ac.x) * rz - mean4[0]) * fast_rcp(std4[0]);
    d.y = ((cy - ac.y) * rw - mean4[1]) * fast_rcp(std4[1]);
    d.z = (__logf(bw * rz) - mean4[2]) * fast_rcp(std4[2]);
    d.w = (__logf(bh * rw) - mean4[3]) * fast_rcp(std4[3]);
    *(float4*)(out_deltas + idx * 4) = d;
}

// ---------------------------------------------------------------------------
extern "C" void kernel_launch(void* const* d_in, const int* in_sizes, int n_in,
                              void* d_out, int out_size, void* d_ws, size_t ws_size,
                              hipStream_t stream) {
    const float* anchors = (const float*)d_in[0];
    const int* labels = (const int*)d_in[1];
    const float* bboxes = (const float*)d_in[2];
    const float* mean4 = (const float*)d_in[3];
    const float* std4 = (const float*)d_in[4];
    const float* thr_p = (const float*)d_in[5];

    const int A = in_sizes[0] / 4;        // 65536
    const int BN = in_sizes[1];           // 800
    const int N = NN;                     // 100
    const int B = BN / N;                 // 8
    const int C = out_size / (B * A) - 4; // 1

    char* ws = (char*)d_ws;
    unsigned long long* packed = (unsigned long long*)ws;                      // [B*N]
    size_t off = ((size_t)B * N * sizeof(unsigned long long) + 255) & ~(size_t)255;
    float* max_iou_anchor = (float*)(ws + off); off += (size_t)B * A * sizeof(float);
    off = (off + 255) & ~(size_t)255;
    int* box_indice = (int*)(ws + off); off += (size_t)B * A * sizeof(int);
    off = (off + 255) & ~(size_t)255;
    int* winner = (int*)(ws + off);

    float* out_conf = (float*)d_out;
    float* out_deltas = out_conf + (size_t)B * A * C;

    bbp_init<<<dim3((B * N + BLOCK - 1) / BLOCK), dim3(BLOCK), 0, stream>>>(packed, B * N);

    dim3 grid((A + BLOCK - 1) / BLOCK, B);
    bbp_match<<<grid, dim3(BLOCK), 0, stream>>>(anchors, bboxes, max_iou_anchor,
                                                box_indice, winner, packed, A, N);

    bbp_scatter<<<dim3((B * N + BLOCK - 1) / BLOCK), dim3(BLOCK), 0, stream>>>(
        packed, winner, A, N, B);

    bbp_finalize<<<grid, dim3(BLOCK), 0, stream>>>(anchors, bboxes, labels, mean4, std4,
                                                   thr_p, max_iou_anchor, box_indice,
                                                   winner, packed, out_conf, out_deltas,
                                                   A, N, C);
}